// Round 16
// baseline (331.249 us; speedup 1.0000x reference)
//
#include <hip/hip_runtime.h>

#define CC 256
#define HH 256
#define WW 256
#define HWV 65536
#define NN 4096
#define SROWS 18     // staged rows: 16-row band + 1 above + 1 below
#define SSTRIDE 260  // padded LDS row stride (words); rows stay 16B-aligned

using u64 = unsigned long long;
using u32 = unsigned int;

__device__ __forceinline__ u32 lbound(const u32* __restrict__ a, u32 n, u32 key) {
    u32 lo = 0, hi = n;
    while (lo < hi) { u32 mid = (lo + hi) >> 1; if (a[mid] < key) lo = mid + 1; else hi = mid; }
    return lo;
}

// ---------------------------------------------------------------------------
// K0: zero the global pass-0 histogram (8 batches x 4096 bins).
__global__ void zero_hist_k(u32* __restrict__ ghist) {
    ghist[blockIdx.x * 1024 + threadIdx.x] = 0u;
}

// ---------------------------------------------------------------------------
// K1: build 48-bit keys AND aggregate the pass-0 (bits 47:36) histogram at
// full parallelism (2048 blocks).
__global__ __launch_bounds__(256) void build_keys_hist_k(const float* __restrict__ pm,
                                                         const int* __restrict__ em,
                                                         u64* __restrict__ keys,
                                                         u32* __restrict__ ghist) {
    __shared__ u32 h[4096];
    const int t = threadIdx.x;
    #pragma unroll
    for (int q = 0; q < 16; ++q) h[t + q * 256] = 0u;
    __syncthreads();
    int i = blockIdx.x * 256 + t;          // flat over 512K = 8 x 65536
    int b = i >> 16;
    float f = (em[i] == 1) ? -fabsf(pm[i]) : -1e30f;
    u32 u = __float_as_uint(f);
    u32 k = (u & 0x80000000u) ? ~u : (u | 0x80000000u);
    u64 K = ((u64)k << 16) | (u64)(0xFFFFu - ((u32)i & 0xFFFFu));
    keys[i] = K;
    atomicAdd(&h[(u32)(K >> 36)], 1u);
    __syncthreads();
    u32* gh = ghist + b * 4096;
    #pragma unroll
    for (int q = 0; q < 16; ++q) {
        u32 v = h[t + q * 256];
        if (v) atomicAdd(&gh[t + q * 256], v);
    }
}

// ---------------------------------------------------------------------------
// K2: blocks 0-7 = per-batch exact top-k. Pass 0 from the precomputed global
// histogram; then SHORTCUT: collect the boundary-bin candidates (expected
// ~800 << 4096) in ONE sweep, bitonic-sort them (zero-padded), and read the
// exact 48-bit threshold — replaces radix passes 1-3. Fallback to the old
// 3-sweep refinement iff candidates > 4096 (degenerate masks only).
// blocks 8-15 = row counting-sort of point_coords.
__global__ __launch_bounds__(1024) void topk_sortpc_k(const u64* __restrict__ keys,
                                                      const u32* __restrict__ ghist,
                                                      const float* __restrict__ pc,
                                                      u32* __restrict__ pixSorted,
                                                      u32* __restrict__ pcSorted,
                                                      float* __restrict__ outCoord,
                                                      float* __restrict__ outIdx) {
    __shared__ u64 sel[NN];
    __shared__ u64 bm[1024];
    __shared__ u32 wp[1024];
    __shared__ u32 s_digit, s_rem, s_cnt, s_C;
    const int t = threadIdx.x;
    if (blockIdx.x < 8) {
        const int b = blockIdx.x;
        const u64* kb = keys + (size_t)b * HWV;
        u32* hist = (u32*)sel;
        // ---- pass 0: load precomputed histogram, suffix-sum, pick digit ----
        #pragma unroll
        for (int q = 0; q < 4; ++q) hist[t + q * 1024] = ghist[b * 4096 + t + q * 1024];
        __syncthreads();
        for (int off = 1; off < 4096; off <<= 1) {   // suffix sums
            u32 v[4];
            #pragma unroll
            for (int q = 0; q < 4; ++q) {
                int i = t + q * 1024;
                v[q] = hist[i];
                if (i + off < 4096) v[q] += hist[i + off];
            }
            __syncthreads();
            #pragma unroll
            for (int q = 0; q < 4; ++q) hist[t + q * 1024] = v[q];
            __syncthreads();
        }
        #pragma unroll
        for (int q = 0; q < 4; ++q) {
            int d = t + q * 1024;
            u32 ge = hist[d];
            u32 gt = (d < 4095) ? hist[d + 1] : 0u;
            if (ge >= NN && gt < NN) { s_digit = (u32)d; s_rem = NN - gt; s_C = ge - gt; }
        }
        __syncthreads();
        const u32 dig = s_digit, rem = s_rem, C = s_C;
        u64 prefix;
        __syncthreads();
        if (C <= (u32)NN) {
            // ---- candidate shortcut: collect digit==dig keys, sort, read threshold ----
            if (t == 0) s_cnt = 0u;
            #pragma unroll
            for (int q = 0; q < 4; ++q) sel[t + q * 1024] = 0ULL;
            __syncthreads();
            for (int i = t; i < HWV; i += 1024) {
                u64 K = kb[i];
                if ((u32)(K >> 36) == dig) { u32 p = atomicAdd(&s_cnt, 1u); sel[p] = K; }
            }
            __syncthreads();
            for (int k = 2; k <= NN; k <<= 1) {           // bitonic desc (zeros sink)
                for (int j = k >> 1; j > 0; j >>= 1) {
                    for (int i = t; i < NN; i += 1024) {
                        int l = i ^ j;
                        if (l > i) {
                            u64 a = sel[i], c = sel[l];
                            bool asc = ((i & k) == 0);
                            if ((a < c) == asc) { sel[i] = c; sel[l] = a; }
                        }
                    }
                    __syncthreads();
                }
            }
            prefix = sel[rem - 1];     // exact 48-bit threshold key
            __syncthreads();
        } else {
            // ---- fallback: old 12-bit refinement sweeps ----
            prefix = (u64)dig;
            u32 remaining = rem;
            for (int r = 1; r < 4; ++r) {
                int shift = 36 - 12 * r;
                #pragma unroll
                for (int q = 0; q < 4; ++q) hist[t + q * 1024] = 0u;
                __syncthreads();
                for (int i = t; i < HWV; i += 1024) {
                    u64 K = kb[i];
                    if ((K >> (shift + 12)) == prefix)
                        atomicAdd(&hist[(u32)((K >> shift) & 0xFFFULL)], 1u);
                }
                __syncthreads();
                for (int off = 1; off < 4096; off <<= 1) {
                    u32 v[4];
                    #pragma unroll
                    for (int q = 0; q < 4; ++q) {
                        int i = t + q * 1024;
                        v[q] = hist[i];
                        if (i + off < 4096) v[q] += hist[i + off];
                    }
                    __syncthreads();
                    #pragma unroll
                    for (int q = 0; q < 4; ++q) hist[t + q * 1024] = v[q];
                    __syncthreads();
                }
                #pragma unroll
                for (int q = 0; q < 4; ++q) {
                    int d = t + q * 1024;
                    u32 ge = hist[d];
                    u32 gt = (d < 4095) ? hist[d + 1] : 0u;
                    if (ge >= remaining && gt < remaining) { s_digit = (u32)d; s_rem = remaining - gt; }
                }
                __syncthreads();
                prefix = (prefix << 12) | (u64)s_digit;
                remaining = s_rem;
                __syncthreads();
            }
        }
        // ---- compaction: exactly 4096 keys satisfy K >= prefix ----
        if (t == 0) s_cnt = 0u;
        __syncthreads();
        for (int i = t; i < HWV; i += 1024) {
            u64 K = kb[i];
            if (K >= prefix) { u32 p = atomicAdd(&s_cnt, 1u); sel[p] = K; }
        }
        __syncthreads();
        for (int k = 2; k <= NN; k <<= 1) {           // bitonic desc
            for (int j = k >> 1; j > 0; j >>= 1) {
                for (int i = t; i < NN; i += 1024) {
                    int l = i ^ j;
                    if (l > i) {
                        u64 a = sel[i], c = sel[l];
                        bool asc = ((i & k) == 0);
                        if ((a < c) == asc) { sel[i] = c; sel[l] = a; }
                    }
                }
                __syncthreads();
            }
        }
        bm[t] = 0ULL;
        __syncthreads();
        #pragma unroll
        for (int q = 0; q < 4; ++q) {
            int r = t + q * 1024;
            u32 pix = 0xFFFFu - (u32)(sel[r] & 0xFFFFULL);
            u32 yi = pix >> 8, xi = pix & 255u;
            outCoord[((size_t)b * NN + r) * 2 + 0] = (float)yi / 255.0f;
            outCoord[((size_t)b * NN + r) * 2 + 1] = (float)xi / 255.0f;
            outIdx[b * NN + r] = (float)pix;   // exact: pix < 2^24
            atomicOr(&bm[pix >> 6], 1ULL << (pix & 63));
        }
        __syncthreads();
        wp[t] = (u32)__popcll(bm[t]);
        __syncthreads();
        for (int off = 1; off < 1024; off <<= 1) {   // inclusive scan
            u32 v = wp[t];
            if (t >= off) v += wp[t - off];
            __syncthreads();
            wp[t] = v;
            __syncthreads();
        }
        #pragma unroll
        for (int q = 0; q < 4; ++q) {
            int r = t + q * 1024;
            u32 pix = 0xFFFFu - (u32)(sel[r] & 0xFFFFULL);
            int w = (int)(pix >> 6);
            u32 pos = wp[w] - (u32)__popcll(bm[w])
                    + (u32)__popcll(bm[w] & ((1ULL << (pix & 63)) - 1ULL));
            pixSorted[b * NN + pos] = (pix << 12) | (u32)r;
        }
    } else {
        const int b = blockIdx.x - 8;
        u32* cellArr = (u32*)sel;
        u32* hist256 = wp;
        u32* cnt     = (u32*)bm;
        if (t < 256) { hist256[t] = 0u; cnt[t] = 0u; }
        __syncthreads();
        for (int n = t; n < NN; n += 1024) {
            float gx = pc[((size_t)b * NN + n) * 2 + 0];
            float gy = pc[((size_t)b * NN + n) * 2 + 1];
            float fx = gx * 256.0f - 0.5f;
            float fy = gy * 256.0f - 0.5f;
            int x0 = (int)floorf(fx), y0 = (int)floorf(fy);
            int xc = min(max(x0, 0), 255), yc = min(max(y0, 0), 255);
            cellArr[n] = ((u32)(yc * 256 + xc) << 12) | (u32)n;
            atomicAdd(&hist256[yc], 1u);
        }
        __syncthreads();
        for (int off = 1; off < 256; off <<= 1) {
            u32 v = 0;
            if (t < 256) { v = hist256[t]; if (t >= off) v += hist256[t - off]; }
            __syncthreads();
            if (t < 256) hist256[t] = v;
            __syncthreads();
        }
        for (int n = t; n < NN; n += 1024) {
            u32 pk = cellArr[n];
            u32 yc = pk >> 20;
            u32 base = (yc > 0) ? hist256[yc - 1] : 0u;
            u32 pos = base + atomicAdd(&cnt[yc], 1u);
            pcSorted[b * NN + pos] = pk;
        }
    }
}

// ---------------------------------------------------------------------------
// Staging: 18-row band slice of one plane, coalesced float4, named registers.
#define STAGE_LOAD(plane) \
    { int idx, r, c4, gr; \
      idx = t;        r = idx >> 6; c4 = idx & 63; gr = min(max(rStart + r, 0), HH - 1); \
      g0 = *(const float4*)((plane) + gr * WW + c4 * 4); \
      idx = t + 256;  r = idx >> 6; c4 = idx & 63; gr = min(max(rStart + r, 0), HH - 1); \
      g1 = *(const float4*)((plane) + gr * WW + c4 * 4); \
      idx = t + 512;  r = idx >> 6; c4 = idx & 63; gr = min(max(rStart + r, 0), HH - 1); \
      g2 = *(const float4*)((plane) + gr * WW + c4 * 4); \
      idx = t + 768;  r = idx >> 6; c4 = idx & 63; gr = min(max(rStart + r, 0), HH - 1); \
      g3 = *(const float4*)((plane) + gr * WW + c4 * 4); \
      if (t < 128) { idx = t + 1024; r = idx >> 6; c4 = idx & 63; gr = min(max(rStart + r, 0), HH - 1); \
      g4 = *(const float4*)((plane) + gr * WW + c4 * 4); } }

#define STAGE_WRITE(dst) \
    { int idx, r, c4; \
      idx = t;        r = idx >> 6; c4 = idx & 63; *(float4*)((dst) + r * SSTRIDE + c4 * 4) = g0; \
      idx = t + 256;  r = idx >> 6; c4 = idx & 63; *(float4*)((dst) + r * SSTRIDE + c4 * 4) = g1; \
      idx = t + 512;  r = idx >> 6; c4 = idx & 63; *(float4*)((dst) + r * SSTRIDE + c4 * 4) = g2; \
      idx = t + 768;  r = idx >> 6; c4 = idx & 63; *(float4*)((dst) + r * SSTRIDE + c4 * 4) = g3; \
      if (t < 128) { idx = t + 1024; r = idx >> 6; c4 = idx & 63; *(float4*)((dst) + r * SSTRIDE + c4 * 4) = g4; } }

// ---------------------------------------------------------------------------
// K3: plane-major staged gather, DOUBLE-BUFFERED: one barrier per plane.
// Iteration j: reads buf[j&1]; writes plane j+1 into buf[(j+1)&1]; the single
// end-of-iteration barrier separates taps(j) (readers of buf[j&1]) from
// iteration j+1's write into buf[j&1]. No loop-carried register arrays.
__global__ __launch_bounds__(256) void plane_gather_k(const float* __restrict__ fm,
                                                      const float* __restrict__ pc,
                                                      const u32* __restrict__ pixSorted,
                                                      const u32* __restrict__ pcSorted,
                                                      float* __restrict__ outLc,
                                                      float* __restrict__ outSc) {
    __shared__ float smA[SROWS * SSTRIDE];
    __shared__ float smB[SROWS * SSTRIDE];
    const int band = blockIdx.x, c0 = blockIdx.y * 32, b = blockIdx.z;
    const int t = threadIdx.x;
    const int rStart = band * 16 - 1;
    const u32 keyLo = (u32)band << 24, keyHi = (u32)(band + 1) << 24;
    const u32* aL = pixSorted + b * NN;
    const u32* aS = pcSorted + b * NN;
    u32 loL = lbound(aL, NN, keyLo), cL = lbound(aL, NN, keyHi) - loL;
    u32 loS = lbound(aS, NN, keyLo), cS = lbound(aS, NN, keyHi) - loS;
    const float* planes = fm + ((size_t)b * CC + c0) * HWV;
    const float* pcb = pc + (size_t)b * NN * 2;

    // ---- decode 2 L + 2 S points into named scalars (no arrays) ----
    int  Lo0 = 0, Lr2 = 0;  float Lw0 = 0, Lw1 = 0, Lw2 = 0, Lw3 = 0, Lwr = 0, Lic = 0;
    int  Mo0 = 0, Mr2 = 0;  float Mw0 = 0, Mw1 = 0, Mw2 = 0, Mw3 = 0, Mwr = 0, Mic = 0;
    int  So0 = 0, Sr1 = 0;  float Sv0 = 0, Sv1 = 0, Sw0 = 0, Sw1 = 0;
    int  To0 = 0, Tr1 = 0;  float Tv0 = 0, Tv1 = 0, Tw0 = 0, Tw1 = 0;
    {
        u32 jl = (u32)t;
        if (jl < cL) {
            u32 pix = aL[loL + jl] >> 12;
            int yi = (int)(pix >> 8), xi = (int)(pix & 255u);
            float cy = (float)yi / 255.0f, cx = (float)xi / 255.0f;   // exact ref pipeline
            int x = (int)(cx * 255.0f), y = (int)(cy * 255.0f);
            int x_min = max(x - 1, 0), x_max = min(x + 2, WW);
            int y_min = max(y - 1, 0), hgt = min(y + 2, HH) - y_min;
            int base2 = min(x_min & ~1, WW - 4);   // even: float2-aligned
            Lw0 = (base2 + 0 >= x_min && base2 + 0 < x_max) ? 1.0f : 0.0f;
            Lw1 = (base2 + 1 >= x_min && base2 + 1 < x_max) ? 1.0f : 0.0f;
            Lw2 = (base2 + 2 >= x_min && base2 + 2 < x_max) ? 1.0f : 0.0f;
            Lw3 = (base2 + 3 >= x_min && base2 + 3 < x_max) ? 1.0f : 0.0f;
            Lo0 = (y_min - rStart) * SSTRIDE + base2;
            Lr2 = ((hgt == 3) ? 2 : 0) * SSTRIDE;  Lwr = (hgt == 3) ? 1.0f : 0.0f;
            Lic = 1.0f / (float)((x_max - x_min) * hgt);
        }
        jl = 256u + (u32)t;
        if (jl < cL) {
            u32 pix = aL[loL + jl] >> 12;
            int yi = (int)(pix >> 8), xi = (int)(pix & 255u);
            float cy = (float)yi / 255.0f, cx = (float)xi / 255.0f;
            int x = (int)(cx * 255.0f), y = (int)(cy * 255.0f);
            int x_min = max(x - 1, 0), x_max = min(x + 2, WW);
            int y_min = max(y - 1, 0), hgt = min(y + 2, HH) - y_min;
            int base2 = min(x_min & ~1, WW - 4);
            Mw0 = (base2 + 0 >= x_min && base2 + 0 < x_max) ? 1.0f : 0.0f;
            Mw1 = (base2 + 1 >= x_min && base2 + 1 < x_max) ? 1.0f : 0.0f;
            Mw2 = (base2 + 2 >= x_min && base2 + 2 < x_max) ? 1.0f : 0.0f;
            Mw3 = (base2 + 3 >= x_min && base2 + 3 < x_max) ? 1.0f : 0.0f;
            Mo0 = (y_min - rStart) * SSTRIDE + base2;
            Mr2 = ((hgt == 3) ? 2 : 0) * SSTRIDE;  Mwr = (hgt == 3) ? 1.0f : 0.0f;
            Mic = 1.0f / (float)((x_max - x_min) * hgt);
        }
        u32 js = (u32)t;
        if (js < cS) {
            u32 sn = aS[loS + js] & 0xFFFu;
            float gx = pcb[2 * sn + 0], gy = pcb[2 * sn + 1];
            float fx = gx * 256.0f - 0.5f, fy = gy * 256.0f - 0.5f;   // exact
            float fx0 = floorf(fx), fy0 = floorf(fy);
            int x0 = (int)fx0, y0 = (int)fy0;
            float wx = fx - fx0, wy = fy - fy0;
            int xb = min(max(x0, 0), WW - 2);
            if (x0 < 0)            { Sv0 = wx;        Sv1 = 0.0f; }
            else if (x0 >= WW - 1) { Sv0 = 0.0f;      Sv1 = 1.0f - wx; }
            else                   { Sv0 = 1.0f - wx; Sv1 = wx; }
            Sw0 = (y0 >= 0)     ? (1.0f - wy) : 0.0f;
            Sw1 = (y0 + 1 < HH) ? wy          : 0.0f;
            int yc0 = min(max(y0, 0), HH - 1), yc1 = min(max(y0 + 1, 0), HH - 1);
            So0 = (yc0 - rStart) * SSTRIDE + xb;
            Sr1 = (yc1 - yc0) * SSTRIDE;
        }
        js = 256u + (u32)t;
        if (js < cS) {
            u32 sn = aS[loS + js] & 0xFFFu;
            float gx = pcb[2 * sn + 0], gy = pcb[2 * sn + 1];
            float fx = gx * 256.0f - 0.5f, fy = gy * 256.0f - 0.5f;
            float fx0 = floorf(fx), fy0 = floorf(fy);
            int x0 = (int)fx0, y0 = (int)fy0;
            float wx = fx - fx0, wy = fy - fy0;
            int xb = min(max(x0, 0), WW - 2);
            if (x0 < 0)            { Tv0 = wx;        Tv1 = 0.0f; }
            else if (x0 >= WW - 1) { Tv0 = 0.0f;      Tv1 = 1.0f - wx; }
            else                   { Tv0 = 1.0f - wx; Tv1 = wx; }
            Tw0 = (y0 >= 0)     ? (1.0f - wy) : 0.0f;
            Tw1 = (y0 + 1 < HH) ? wy          : 0.0f;
            int yc0 = min(max(y0, 0), HH - 1), yc1 = min(max(y0 + 1, 0), HH - 1);
            To0 = (yc0 - rStart) * SSTRIDE + xb;
            Tr1 = (yc1 - yc0) * SSTRIDE;
        }
    }

    float4 g0, g1, g2, g3, g4;
    STAGE_LOAD(planes)
    STAGE_WRITE(smA)
    __syncthreads();

    #pragma unroll 1
    for (int j = 0; j < 32; ++j) {
        const float* sm = (j & 1) ? smB : smA;
        float* smw = (j & 1) ? smA : smB;
        if (j + 1 < 32) { const float* np = planes + (size_t)(j + 1) * HWV; STAGE_LOAD(np) }
        // ---- taps from LDS, written immediately (sorted-position layout) ----
        float* oL = outLc + ((size_t)(b * CC + c0 + j)) * NN + loL;
        float* oS = outSc + ((size_t)(b * CC + c0 + j)) * NN + loS;
        if ((u32)t < cL) {
            float2 a0 = *(const float2*)(sm + Lo0);
            float2 b0 = *(const float2*)(sm + Lo0 + 2);
            float2 a1 = *(const float2*)(sm + Lo0 + SSTRIDE);
            float2 b1 = *(const float2*)(sm + Lo0 + SSTRIDE + 2);
            float2 a2 = *(const float2*)(sm + Lo0 + Lr2);
            float2 b2 = *(const float2*)(sm + Lo0 + Lr2 + 2);
            float r0 = a0.x * Lw0 + a0.y * Lw1 + b0.x * Lw2 + b0.y * Lw3;
            float r1 = a1.x * Lw0 + a1.y * Lw1 + b1.x * Lw2 + b1.y * Lw3;
            float r2 = a2.x * Lw0 + a2.y * Lw1 + b2.x * Lw2 + b2.y * Lw3;
            oL[t] = (r0 + r1 + Lwr * r2) * Lic;
        }
        if (256u + (u32)t < cL) {
            float2 a0 = *(const float2*)(sm + Mo0);
            float2 b0 = *(const float2*)(sm + Mo0 + 2);
            float2 a1 = *(const float2*)(sm + Mo0 + SSTRIDE);
            float2 b1 = *(const float2*)(sm + Mo0 + SSTRIDE + 2);
            float2 a2 = *(const float2*)(sm + Mo0 + Mr2);
            float2 b2 = *(const float2*)(sm + Mo0 + Mr2 + 2);
            float r0 = a0.x * Mw0 + a0.y * Mw1 + b0.x * Mw2 + b0.y * Mw3;
            float r1 = a1.x * Mw0 + a1.y * Mw1 + b1.x * Mw2 + b1.y * Mw3;
            float r2 = a2.x * Mw0 + a2.y * Mw1 + b2.x * Mw2 + b2.y * Mw3;
            oL[256 + t] = (r0 + r1 + Mwr * r2) * Mic;
        }
        if ((u32)t < cS) {
            oS[t] = Sw0 * (sm[So0] * Sv0 + sm[So0 + 1] * Sv1)
                  + Sw1 * (sm[So0 + Sr1] * Sv0 + sm[So0 + Sr1 + 1] * Sv1);
        }
        if (256u + (u32)t < cS) {
            oS[256 + t] = Tw0 * (sm[To0] * Tv0 + sm[To0 + 1] * Tv1)
                        + Tw1 * (sm[To0 + Tr1] * Tv0 + sm[To0 + Tr1 + 1] * Tv1);
        }
        if (j + 1 < 32) { STAGE_WRITE(smw) }
        __syncthreads();
    }

    // ---- overflow epilogue (cL/cS > 512: >16 sigma, never in practice) ----
    for (u32 jl = 512 + (u32)t; jl < cL; jl += 256) {
        u32 pix = aL[loL + jl] >> 12;
        int yi = (int)(pix >> 8), xi = (int)(pix & 255u);
        float cy = (float)yi / 255.0f, cx = (float)xi / 255.0f;
        int x = (int)(cx * 255.0f), y = (int)(cy * 255.0f);
        int x_min = max(x - 1, 0), x_max = min(x + 2, WW);
        int y_min = max(y - 1, 0), y_max = min(y + 2, HH);
        float ic = 1.0f / (float)((x_max - x_min) * (y_max - y_min));
        for (int j = 0; j < 32; ++j) {
            const float* p = planes + (size_t)j * HWV;
            float s = 0.0f;
            for (int yy = y_min; yy < y_max; ++yy)
                for (int xx = x_min; xx < x_max; ++xx) s += p[yy * WW + xx];
            outLc[((size_t)(b * CC + c0 + j)) * NN + loL + jl] = s * ic;
        }
    }
    for (u32 js = 512 + (u32)t; js < cS; js += 256) {
        u32 sn = aS[loS + js] & 0xFFFu;
        float gx = pcb[2 * sn + 0], gy = pcb[2 * sn + 1];
        float fx = gx * 256.0f - 0.5f, fy = gy * 256.0f - 0.5f;
        float fx0 = floorf(fx), fy0 = floorf(fy);
        int x0 = (int)fx0, y0 = (int)fy0;
        float wx = fx - fx0, wy = fy - fy0;
        int xb = min(max(x0, 0), WW - 2);
        float v0, v1, r0, r1;
        if (x0 < 0)            { v0 = wx;        v1 = 0.0f; }
        else if (x0 >= WW - 1) { v0 = 0.0f;      v1 = 1.0f - wx; }
        else                   { v0 = 1.0f - wx; v1 = wx; }
        r0 = (y0 >= 0)     ? (1.0f - wy) : 0.0f;
        r1 = (y0 + 1 < HH) ? wy          : 0.0f;
        int yc0 = min(max(y0, 0), HH - 1), yc1 = min(max(y0 + 1, 0), HH - 1);
        int o0 = yc0 * WW + xb, o1 = yc1 * WW + xb;
        for (int j = 0; j < 32; ++j) {
            const float* p = planes + (size_t)j * HWV;
            outSc[((size_t)(b * CC + c0 + j)) * NN + loS + js] =
                r0 * (p[o0] * v0 + p[o0 + 1] * v1) + r1 * (p[o1] * v0 + p[o1 + 1] * v1);
        }
    }
}

// ---------------------------------------------------------------------------
// K4: unpermute L: outL[b][c][rank[spos]] = outLc[b][c][spos] via LDS scatter.
__global__ __launch_bounds__(256) void unpermL_k(const float* __restrict__ outLc,
                                                 const u32* __restrict__ pixSorted,
                                                 float* __restrict__ outL) {
    __shared__ float row[NN];
    const int c = blockIdx.x, b = blockIdx.y;
    const int t = threadIdx.x;
    const float* in = outLc + ((size_t)(b * CC + c)) * NN;
    for (int j = t; j < NN; j += 256)
        row[pixSorted[b * NN + j] & 0xFFFu] = in[j];
    __syncthreads();
    float* o = outL + ((size_t)(b * CC + c)) * NN;
    for (int i = t; i < NN; i += 256) o[i] = row[i];
}

// ---------------------------------------------------------------------------
// K5: unpermute S: outS[b][n[spos]][c] = outSc[b][c][spos] (tile transpose).
__global__ __launch_bounds__(256) void unpermS_k(const float* __restrict__ outSc,
                                                 const u32* __restrict__ pcSorted,
                                                 float* __restrict__ outS) {
    __shared__ float tile[32][257];
    __shared__ u32 ns[256];
    const int j0 = blockIdx.x * 256, c0 = blockIdx.y * 32, b = blockIdx.z;
    const int t = threadIdx.x;
    ns[t] = pcSorted[b * NN + j0 + t] & 0xFFFu;
    for (int i = 0; i < 32; ++i)
        tile[i][t] = outSc[((size_t)(b * CC + c0 + i)) * NN + j0 + t];
    __syncthreads();
    for (int idx = t; idx < 8192; idx += 256) {
        int p = idx >> 5, k = idx & 31;
        outS[((size_t)b * NN + ns[p]) * CC + c0 + k] = tile[k][p];
    }
}

// ---------------------------------------------------------------------------
// Fallback kernels (no-ws path): round-13 proven pipeline.
__global__ void build_keys_k(const float* __restrict__ pm, const int* __restrict__ em,
                             u64* __restrict__ keys) {
    int i = blockIdx.x * blockDim.x + threadIdx.x;
    float f = (em[i] == 1) ? -fabsf(pm[i]) : -1e30f;
    u32 u = __float_as_uint(f);
    u32 k = (u & 0x80000000u) ? ~u : (u | 0x80000000u);
    u32 pix = (u32)i & 0xFFFFu;
    keys[i] = ((u64)k << 16) | (u64)(0xFFFFu - pix);
}

__global__ __launch_bounds__(1024) void topk_sortpc_old_k(const u64* __restrict__ keys,
                                                          const float* __restrict__ pc,
                                                          u32* __restrict__ stash,
                                                          u32* __restrict__ pixSorted,
                                                          u32* __restrict__ pcSorted) {
    __shared__ u64 sel[NN];
    __shared__ u64 bm[1024];
    __shared__ u32 wp[1024];
    __shared__ u32 s_digit, s_rem, s_cnt;
    const int t = threadIdx.x;
    if (blockIdx.x < 8) {
        const int b = blockIdx.x;
        const u64* kb = keys + (size_t)b * HWV;
        u32* hist = (u32*)sel;
        u64 prefix = 0ULL;
        u32 remaining = NN;
        for (int r = 0; r < 4; ++r) {
            int shift = 36 - 12 * r;
            #pragma unroll
            for (int q = 0; q < 4; ++q) hist[t + q * 1024] = 0u;
            __syncthreads();
            for (int i = t; i < HWV; i += 1024) {
                u64 K = kb[i];
                if ((K >> (shift + 12)) == prefix)
                    atomicAdd(&hist[(u32)((K >> shift) & 0xFFFULL)], 1u);
            }
            __syncthreads();
            for (int off = 1; off < 4096; off <<= 1) {
                u32 v[4];
                #pragma unroll
                for (int q = 0; q < 4; ++q) {
                    int i = t + q * 1024;
                    v[q] = hist[i];
                    if (i + off < 4096) v[q] += hist[i + off];
                }
                __syncthreads();
                #pragma unroll
                for (int q = 0; q < 4; ++q) hist[t + q * 1024] = v[q];
                __syncthreads();
            }
            #pragma unroll
            for (int q = 0; q < 4; ++q) {
                int d = t + q * 1024;
                u32 ge = hist[d];
                u32 gt = (d < 4095) ? hist[d + 1] : 0u;
                if (ge >= remaining && gt < remaining) { s_digit = (u32)d; s_rem = remaining - gt; }
            }
            __syncthreads();
            prefix = (prefix << 12) | (u64)s_digit;
            remaining = s_rem;
            __syncthreads();
        }
        if (t == 0) s_cnt = 0u;
        __syncthreads();
        for (int i = t; i < HWV; i += 1024) {
            u64 K = kb[i];
            if (K >= prefix) { u32 p = atomicAdd(&s_cnt, 1u); sel[p] = K; }
        }
        __syncthreads();
        for (int k = 2; k <= NN; k <<= 1) {
            for (int j = k >> 1; j > 0; j >>= 1) {
                for (int i = t; i < NN; i += 1024) {
                    int l = i ^ j;
                    if (l > i) {
                        u64 a = sel[i], c = sel[l];
                        bool asc = ((i & k) == 0);
                        if ((a < c) == asc) { sel[i] = c; sel[l] = a; }
                    }
                }
                __syncthreads();
            }
        }
        bm[t] = 0ULL;
        __syncthreads();
        #pragma unroll
        for (int q = 0; q < 4; ++q) {
            int r = t + q * 1024;
            u32 pix = 0xFFFFu - (u32)(sel[r] & 0xFFFFULL);
            stash[b * NN + r] = pix;
            atomicOr(&bm[pix >> 6], 1ULL << (pix & 63));
        }
        __syncthreads();
        wp[t] = (u32)__popcll(bm[t]);
        __syncthreads();
        for (int off = 1; off < 1024; off <<= 1) {
            u32 v = wp[t];
            if (t >= off) v += wp[t - off];
            __syncthreads();
            wp[t] = v;
            __syncthreads();
        }
        #pragma unroll
        for (int q = 0; q < 4; ++q) {
            int r = t + q * 1024;
            u32 pix = 0xFFFFu - (u32)(sel[r] & 0xFFFFULL);
            int w = (int)(pix >> 6);
            u32 pos = wp[w] - (u32)__popcll(bm[w])
                    + (u32)__popcll(bm[w] & ((1ULL << (pix & 63)) - 1ULL));
            pixSorted[b * NN + pos] = (pix << 12) | (u32)r;
        }
    } else {
        const int b = blockIdx.x - 8;
        u32* cellArr = (u32*)sel;
        u32* hist256 = wp;
        u32* cnt     = (u32*)bm;
        if (t < 256) { hist256[t] = 0u; cnt[t] = 0u; }
        __syncthreads();
        for (int n = t; n < NN; n += 1024) {
            float gx = pc[((size_t)b * NN + n) * 2 + 0];
            float gy = pc[((size_t)b * NN + n) * 2 + 1];
            float fx = gx * 256.0f - 0.5f;
            float fy = gy * 256.0f - 0.5f;
            int x0 = (int)floorf(fx), y0 = (int)floorf(fy);
            int xc = min(max(x0, 0), 255), yc = min(max(y0, 0), 255);
            cellArr[n] = ((u32)(yc * 256 + xc) << 12) | (u32)n;
            atomicAdd(&hist256[yc], 1u);
        }
        __syncthreads();
        for (int off = 1; off < 256; off <<= 1) {
            u32 v = 0;
            if (t < 256) { v = hist256[t]; if (t >= off) v += hist256[t - off]; }
            __syncthreads();
            if (t < 256) hist256[t] = v;
            __syncthreads();
        }
        for (int n = t; n < NN; n += 1024) {
            u32 pk = cellArr[n];
            u32 yc = pk >> 20;
            u32 base = (yc > 0) ? hist256[yc - 1] : 0u;
            u32 pos = base + atomicAdd(&cnt[yc], 1u);
            pcSorted[b * NN + pos] = pk;
        }
    }
}

template<int MODE>
__global__ __launch_bounds__(256, 4) void gather_k(const float* __restrict__ fm,
                                                   const float* __restrict__ pc,
                                                   const u32* __restrict__ pixSorted,
                                                   const u32* __restrict__ pcSorted,
                                                   float* __restrict__ outLp,
                                                   float* __restrict__ outS) {
    __shared__ float tile[256][33];
    __shared__ u32 pidx[256];
    const int b = blockIdx.z, j0 = blockIdx.x * 256, t = threadIdx.x;
    bool doL = (MODE == 1); int c0 = blockIdx.y * 32;
    const float* planes = fm + ((size_t)b * CC + c0) * HWV;
    if (doL) {
        u32 packed = pixSorted[b * NN + j0 + t];
        u32 pix = packed >> 12;
        pidx[t] = packed & 0xFFFu;
        int yi = (int)(pix >> 8), xi = (int)(pix & 255u);
        float cy = (float)yi / 255.0f, cx = (float)xi / 255.0f;
        int x = (int)(cx * 255.0f), y = (int)(cy * 255.0f);
        int x_min = max(x - 1, 0), x_max = min(x + 2, WW);
        int y_min = max(y - 1, 0), y_max = min(y + 2, HH);
        int base = min(x_min & ~3, WW - 8);
        float w8[8];
        #pragma unroll
        for (int i = 0; i < 8; ++i)
            w8[i] = (base + i >= x_min && base + i < x_max) ? 1.0f : 0.0f;
        float wr2 = (y_min + 2 < y_max) ? 1.0f : 0.0f;
        int o0 = y_min * WW + base, o1 = o0 + WW;
        int o2 = min(y_min + 2, HH - 1) * WW + base;
        float invc = 1.0f / (float)((x_max - x_min) * (y_max - y_min));
        #pragma unroll 2
        for (int j = 0; j < 32; ++j) {
            const float* p = planes + (size_t)j * HWV;
            float4 a0 = *(const float4*)(p + o0), b0 = *(const float4*)(p + o0 + 4);
            float4 a1 = *(const float4*)(p + o1), b1 = *(const float4*)(p + o1 + 4);
            float4 a2 = *(const float4*)(p + o2), b2 = *(const float4*)(p + o2 + 4);
            float s0 = a0.x * w8[0] + a0.y * w8[1] + a0.z * w8[2] + a0.w * w8[3]
                     + b0.x * w8[4] + b0.y * w8[5] + b0.z * w8[6] + b0.w * w8[7];
            float s1 = a1.x * w8[0] + a1.y * w8[1] + a1.z * w8[2] + a1.w * w8[3]
                     + b1.x * w8[4] + b1.y * w8[5] + b1.z * w8[6] + b1.w * w8[7];
            float s2 = a2.x * w8[0] + a2.y * w8[1] + a2.z * w8[2] + a2.w * w8[3]
                     + b2.x * w8[4] + b2.y * w8[5] + b2.z * w8[6] + b2.w * w8[7];
            tile[t][j] = (s0 + s1 + wr2 * s2) * invc;
        }
        __syncthreads();
        for (int idx = t; idx < 8192; idx += 256) {
            int p = idx >> 5, k = idx & 31;
            outLp[((size_t)b * NN + pidx[p]) * CC + c0 + k] = tile[p][k];
        }
    } else {
        int n = (int)(pcSorted[b * NN + j0 + t] & 0xFFFu);
        pidx[t] = (u32)n;
        float gx = pc[((size_t)b * NN + n) * 2 + 0];
        float gy = pc[((size_t)b * NN + n) * 2 + 1];
        float fx = gx * 256.0f - 0.5f, fy = gy * 256.0f - 0.5f;
        float fx0 = floorf(fx), fy0 = floorf(fy);
        int x0 = (int)fx0, y0 = (int)fy0;
        float wx = fx - fx0, wy = fy - fy0;
        int xb = min(max(x0, 0), WW - 2);
        float wv0, wv1;
        if (x0 < 0)            { wv0 = wx;        wv1 = 0.0f; }
        else if (x0 >= WW - 1) { wv0 = 0.0f;      wv1 = 1.0f - wx; }
        else                   { wv0 = 1.0f - wx; wv1 = wx; }
        float wr0 = (y0 >= 0)     ? (1.0f - wy) : 0.0f;
        float wr1 = (y0 + 1 < HH) ? wy          : 0.0f;
        int yc0 = min(max(y0, 0), HH - 1), yc1 = min(max(y0 + 1, 0), HH - 1);
        int o0 = yc0 * WW + xb, o1 = yc1 * WW + xb;
        #pragma unroll 4
        for (int j = 0; j < 32; ++j) {
            const float* p = planes + (size_t)j * HWV;
            tile[t][j] = wr0 * (p[o0] * wv0 + p[o0 + 1] * wv1)
                       + wr1 * (p[o1] * wv0 + p[o1 + 1] * wv1);
        }
        __syncthreads();
        for (int idx = t; idx < 8192; idx += 256) {
            int p = idx >> 5, k = idx & 31;
            outS[((size_t)b * NN + pidx[p]) * CC + c0 + k] = tile[p][k];
        }
    }
}

__global__ __launch_bounds__(256) void transpose_k(const float* __restrict__ outLp,
                                                   float* __restrict__ outL) {
    __shared__ float tile[256][33];
    const int b = blockIdx.z, c0 = blockIdx.y * 32, r0 = blockIdx.x * 256;
    const int t = threadIdx.x;
    for (int idx = t; idx < 8192; idx += 256) {
        int p = idx >> 5, k = idx & 31;
        tile[p][k] = outLp[((size_t)b * NN + r0 + p) * CC + c0 + k];
    }
    __syncthreads();
    for (int idx = t; idx < 8192; idx += 256) {
        int cl = idx >> 8, col = idx & 255;
        outL[((size_t)b * CC + c0 + cl) * NN + r0 + col] = tile[col][cl];
    }
}

__global__ void emit_k(const u32* __restrict__ stash, float* __restrict__ outCoord,
                       float* __restrict__ outIdx) {
    int i = blockIdx.x * blockDim.x + threadIdx.x;
    u32 p = stash[i];
    u32 yi = p >> 8, xi = p & 255u;
    outCoord[(size_t)i * 2 + 0] = (float)yi / 255.0f;
    outCoord[(size_t)i * 2 + 1] = (float)xi / 255.0f;
    outIdx[i] = (float)p;
}

extern "C" void kernel_launch(void* const* d_in, const int* in_sizes, int n_in,
                              void* d_out, int out_size, void* d_ws, size_t ws_size,
                              hipStream_t stream) {
    const float* fm = (const float*)d_in[0];   // (8,256,256,256) f32
    const float* pm = (const float*)d_in[1];   // (8,1,256,256) f32
    const int*   em = (const int*)d_in[2];     // (8,256,256) i32
    const float* pc = (const float*)d_in[3];   // (8,4096,2) f32
    (void)in_sizes; (void)n_in; (void)out_size;

    float* out      = (float*)d_out;
    float* outL     = out;                         // local_feats (8,256,4096)
    float* outS     = out + (size_t)8388608;       // sampled     (8,4096,256)
    float* outCoord = out + (size_t)16777216;      // coords      (8,4096,2)
    float* outIdx   = out + (size_t)16842752;      // idx         (8,4096)

    const size_t need_ws = (size_t)80 * 1024 * 1024;
    bool ws_ok = ws_size >= need_ws;

    if (ws_ok) {
        char* w = (char*)d_ws;
        u64* keys      = (u64*)w;                                // 4 MB
        u32* ghist     = (u32*)(w + (size_t)4096 * 1024);        // 128 KB
        u32* pixSorted = (u32*)(w + (size_t)4300 * 1024);        // 128 KB
        u32* pcSorted  = (u32*)(w + (size_t)4600 * 1024);        // 128 KB
        float* outLc   = (float*)(w + (size_t)5  * 1024 * 1024); // 33.5 MB
        float* outSc   = (float*)(w + (size_t)40 * 1024 * 1024); // 33.5 MB

        hipLaunchKernelGGL(zero_hist_k, dim3(32), dim3(1024), 0, stream, ghist);
        hipLaunchKernelGGL(build_keys_hist_k, dim3(2048), dim3(256), 0, stream,
                           pm, em, keys, ghist);
        hipLaunchKernelGGL(topk_sortpc_k, dim3(16), dim3(1024), 0, stream,
                           keys, ghist, pc, pixSorted, pcSorted, outCoord, outIdx);
        hipLaunchKernelGGL(plane_gather_k, dim3(16, 8, 8), dim3(256), 0, stream,
                           fm, pc, pixSorted, pcSorted, outLc, outSc);
        hipLaunchKernelGGL(unpermL_k, dim3(256, 8), dim3(256), 0, stream,
                           outLc, pixSorted, outL);
        hipLaunchKernelGGL(unpermS_k, dim3(16, 8, 8), dim3(256), 0, stream,
                           outSc, pcSorted, outS);
    } else {
        // alias scheme: keys/outLp in seg1 (final writer = gather<2>),
        // pixSorted/pcSorted in seg2 (final writer = emit), stash in seg3.
        u64* keys      = (u64*)outS;
        u32* stash     = (u32*)outIdx;
        u32* pixSorted = (u32*)outCoord;
        u32* pcSorted  = pixSorted + 32768;
        float* outLp   = outS;

        hipLaunchKernelGGL(build_keys_k, dim3(2048), dim3(256), 0, stream, pm, em, keys);
        hipLaunchKernelGGL(topk_sortpc_old_k, dim3(16), dim3(1024), 0, stream,
                           keys, pc, stash, pixSorted, pcSorted);
        hipLaunchKernelGGL((gather_k<1>), dim3(16, 8, 8), dim3(256), 0, stream,
                           fm, pc, pixSorted, pcSorted, outLp, outS);
        hipLaunchKernelGGL(transpose_k, dim3(16, 8, 8), dim3(256), 0, stream, outLp, outL);
        hipLaunchKernelGGL((gather_k<2>), dim3(16, 8, 8), dim3(256), 0, stream,
                           fm, pc, pixSorted, pcSorted, outS, outS);
        hipLaunchKernelGGL(emit_k, dim3(128), dim3(256), 0, stream, stash, outCoord, outIdx);
    }
}

// Round 17
// 311.153 us; speedup vs baseline: 1.0646x; 1.0646x over previous
//
#include <hip/hip_runtime.h>

#define CC 256
#define HH 256
#define WW 256
#define HWV 65536
#define NN 4096
#define SROWS 18     // staged rows: 16-row band + 1 above + 1 below
#define SSTRIDE 260  // padded LDS row stride (words); rows stay 16B-aligned

using u64 = unsigned long long;
using u32 = unsigned int;

__device__ __forceinline__ u32 lbound(const u32* __restrict__ a, u32 n, u32 key) {
    u32 lo = 0, hi = n;
    while (lo < hi) { u32 mid = (lo + hi) >> 1; if (a[mid] < key) lo = mid + 1; else hi = mid; }
    return lo;
}

// ---------------------------------------------------------------------------
// K0: zero the global pass-0 histogram (8 batches x 4096 bins).
__global__ void zero_hist_k(u32* __restrict__ ghist) {
    ghist[blockIdx.x * 1024 + threadIdx.x] = 0u;
}

// ---------------------------------------------------------------------------
// K1: build 48-bit keys AND aggregate the pass-0 (bits 47:36) histogram at
// full parallelism (2048 blocks). Per-block LDS histogram, flush non-zero
// bins with global atomics. Each block's 256 elements share one batch.
__global__ __launch_bounds__(256) void build_keys_hist_k(const float* __restrict__ pm,
                                                         const int* __restrict__ em,
                                                         u64* __restrict__ keys,
                                                         u32* __restrict__ ghist) {
    __shared__ u32 h[4096];
    const int t = threadIdx.x;
    #pragma unroll
    for (int q = 0; q < 16; ++q) h[t + q * 256] = 0u;
    __syncthreads();
    int i = blockIdx.x * 256 + t;          // flat over 512K = 8 x 65536
    int b = i >> 16;
    float f = (em[i] == 1) ? -fabsf(pm[i]) : -1e30f;
    u32 u = __float_as_uint(f);
    u32 k = (u & 0x80000000u) ? ~u : (u | 0x80000000u);
    u64 K = ((u64)k << 16) | (u64)(0xFFFFu - ((u32)i & 0xFFFFu));
    keys[i] = K;
    atomicAdd(&h[(u32)(K >> 36)], 1u);
    __syncthreads();
    u32* gh = ghist + b * 4096;
    #pragma unroll
    for (int q = 0; q < 16; ++q) {
        u32 v = h[t + q * 256];
        if (v) atomicAdd(&gh[t + q * 256], v);
    }
}

// ---------------------------------------------------------------------------
// K2: blocks 0-7 = per-batch exact top-k: pass 0 from the precomputed global
// histogram, then 3 more 12-bit radix sweeps, desc bitonic (ranks),
// bitmap/popcount spatial emit; writes coords/idx directly.
// blocks 8-15 = row counting-sort of point_coords.
__global__ __launch_bounds__(1024) void topk_sortpc_k(const u64* __restrict__ keys,
                                                      const u32* __restrict__ ghist,
                                                      const float* __restrict__ pc,
                                                      u32* __restrict__ pixSorted,
                                                      u32* __restrict__ pcSorted,
                                                      float* __restrict__ outCoord,
                                                      float* __restrict__ outIdx) {
    __shared__ u64 sel[NN];
    __shared__ u64 bm[1024];
    __shared__ u32 wp[1024];
    __shared__ u32 s_digit, s_rem, s_cnt;
    const int t = threadIdx.x;
    if (blockIdx.x < 8) {
        const int b = blockIdx.x;
        const u64* kb = keys + (size_t)b * HWV;
        u32* hist = (u32*)sel;
        u64 prefix = 0ULL;
        u32 remaining = NN;
        for (int r = 0; r < 4; ++r) {
            int shift = 36 - 12 * r;
            if (r == 0) {
                #pragma unroll
                for (int q = 0; q < 4; ++q) hist[t + q * 1024] = ghist[b * 4096 + t + q * 1024];
                __syncthreads();
            } else {
                #pragma unroll
                for (int q = 0; q < 4; ++q) hist[t + q * 1024] = 0u;
                __syncthreads();
                for (int i = t; i < HWV; i += 1024) {
                    u64 K = kb[i];
                    if ((K >> (shift + 12)) == prefix)
                        atomicAdd(&hist[(u32)((K >> shift) & 0xFFFULL)], 1u);
                }
                __syncthreads();
            }
            for (int off = 1; off < 4096; off <<= 1) {   // suffix sums
                u32 v[4];
                #pragma unroll
                for (int q = 0; q < 4; ++q) {
                    int i = t + q * 1024;
                    v[q] = hist[i];
                    if (i + off < 4096) v[q] += hist[i + off];
                }
                __syncthreads();
                #pragma unroll
                for (int q = 0; q < 4; ++q) hist[t + q * 1024] = v[q];
                __syncthreads();
            }
            #pragma unroll
            for (int q = 0; q < 4; ++q) {
                int d = t + q * 1024;
                u32 ge = hist[d];
                u32 gt = (d < 4095) ? hist[d + 1] : 0u;
                if (ge >= remaining && gt < remaining) { s_digit = (u32)d; s_rem = remaining - gt; }
            }
            __syncthreads();
            prefix = (prefix << 12) | (u64)s_digit;
            remaining = s_rem;
            __syncthreads();
        }
        if (t == 0) s_cnt = 0u;
        __syncthreads();
        for (int i = t; i < HWV; i += 1024) {
            u64 K = kb[i];
            if (K >= prefix) { u32 p = atomicAdd(&s_cnt, 1u); sel[p] = K; }
        }
        __syncthreads();
        for (int k = 2; k <= NN; k <<= 1) {           // bitonic desc
            for (int j = k >> 1; j > 0; j >>= 1) {
                for (int i = t; i < NN; i += 1024) {
                    int l = i ^ j;
                    if (l > i) {
                        u64 a = sel[i], c = sel[l];
                        bool asc = ((i & k) == 0);
                        if ((a < c) == asc) { sel[i] = c; sel[l] = a; }
                    }
                }
                __syncthreads();
            }
        }
        bm[t] = 0ULL;
        __syncthreads();
        #pragma unroll
        for (int q = 0; q < 4; ++q) {
            int r = t + q * 1024;
            u32 pix = 0xFFFFu - (u32)(sel[r] & 0xFFFFULL);
            u32 yi = pix >> 8, xi = pix & 255u;
            outCoord[((size_t)b * NN + r) * 2 + 0] = (float)yi / 255.0f;
            outCoord[((size_t)b * NN + r) * 2 + 1] = (float)xi / 255.0f;
            outIdx[b * NN + r] = (float)pix;   // exact: pix < 2^24
            atomicOr(&bm[pix >> 6], 1ULL << (pix & 63));
        }
        __syncthreads();
        wp[t] = (u32)__popcll(bm[t]);
        __syncthreads();
        for (int off = 1; off < 1024; off <<= 1) {   // inclusive scan
            u32 v = wp[t];
            if (t >= off) v += wp[t - off];
            __syncthreads();
            wp[t] = v;
            __syncthreads();
        }
        #pragma unroll
        for (int q = 0; q < 4; ++q) {
            int r = t + q * 1024;
            u32 pix = 0xFFFFu - (u32)(sel[r] & 0xFFFFULL);
            int w = (int)(pix >> 6);
            u32 pos = wp[w] - (u32)__popcll(bm[w])
                    + (u32)__popcll(bm[w] & ((1ULL << (pix & 63)) - 1ULL));
            pixSorted[b * NN + pos] = (pix << 12) | (u32)r;
        }
    } else {
        const int b = blockIdx.x - 8;
        u32* cellArr = (u32*)sel;
        u32* hist256 = wp;
        u32* cnt     = (u32*)bm;
        if (t < 256) { hist256[t] = 0u; cnt[t] = 0u; }
        __syncthreads();
        for (int n = t; n < NN; n += 1024) {
            float gx = pc[((size_t)b * NN + n) * 2 + 0];
            float gy = pc[((size_t)b * NN + n) * 2 + 1];
            float fx = gx * 256.0f - 0.5f;
            float fy = gy * 256.0f - 0.5f;
            int x0 = (int)floorf(fx), y0 = (int)floorf(fy);
            int xc = min(max(x0, 0), 255), yc = min(max(y0, 0), 255);
            cellArr[n] = ((u32)(yc * 256 + xc) << 12) | (u32)n;
            atomicAdd(&hist256[yc], 1u);
        }
        __syncthreads();
        for (int off = 1; off < 256; off <<= 1) {
            u32 v = 0;
            if (t < 256) { v = hist256[t]; if (t >= off) v += hist256[t - off]; }
            __syncthreads();
            if (t < 256) hist256[t] = v;
            __syncthreads();
        }
        for (int n = t; n < NN; n += 1024) {
            u32 pk = cellArr[n];
            u32 yc = pk >> 20;
            u32 base = (yc > 0) ? hist256[yc - 1] : 0u;
            u32 pos = base + atomicAdd(&cnt[yc], 1u);
            pcSorted[b * NN + pos] = pk;
        }
    }
}

// ---------------------------------------------------------------------------
// Staging: 18-row band slice of one plane, coalesced float4, named registers.
#define STAGE_LOAD(plane) \
    { int idx, r, c4, gr; \
      idx = t;        r = idx >> 6; c4 = idx & 63; gr = min(max(rStart + r, 0), HH - 1); \
      g0 = *(const float4*)((plane) + gr * WW + c4 * 4); \
      idx = t + 256;  r = idx >> 6; c4 = idx & 63; gr = min(max(rStart + r, 0), HH - 1); \
      g1 = *(const float4*)((plane) + gr * WW + c4 * 4); \
      idx = t + 512;  r = idx >> 6; c4 = idx & 63; gr = min(max(rStart + r, 0), HH - 1); \
      g2 = *(const float4*)((plane) + gr * WW + c4 * 4); \
      idx = t + 768;  r = idx >> 6; c4 = idx & 63; gr = min(max(rStart + r, 0), HH - 1); \
      g3 = *(const float4*)((plane) + gr * WW + c4 * 4); \
      if (t < 128) { idx = t + 1024; r = idx >> 6; c4 = idx & 63; gr = min(max(rStart + r, 0), HH - 1); \
      g4 = *(const float4*)((plane) + gr * WW + c4 * 4); } }

#define STAGE_WRITE() \
    { int idx, r, c4; \
      idx = t;        r = idx >> 6; c4 = idx & 63; *(float4*)(sm + r * SSTRIDE + c4 * 4) = g0; \
      idx = t + 256;  r = idx >> 6; c4 = idx & 63; *(float4*)(sm + r * SSTRIDE + c4 * 4) = g1; \
      idx = t + 512;  r = idx >> 6; c4 = idx & 63; *(float4*)(sm + r * SSTRIDE + c4 * 4) = g2; \
      idx = t + 768;  r = idx >> 6; c4 = idx & 63; *(float4*)(sm + r * SSTRIDE + c4 * 4) = g3; \
      if (t < 128) { idx = t + 1024; r = idx >> 6; c4 = idx & 63; *(float4*)(sm + r * SSTRIDE + c4 * 4) = g4; } }

// ---------------------------------------------------------------------------
// K3: plane-major staged gather (round-13 structure, proven no-spill).
// Block = (band, 32-plane group, b). One plane staged at a time, reg-prefetch
// of plane j+1 before plane-j taps. L taps 6x ds_read_b64 via even-aligned
// 4-wide windows. Results written immediately in sorted-position layout.
__global__ __launch_bounds__(256) void plane_gather_k(const float* __restrict__ fm,
                                                      const float* __restrict__ pc,
                                                      const u32* __restrict__ pixSorted,
                                                      const u32* __restrict__ pcSorted,
                                                      float* __restrict__ outLc,
                                                      float* __restrict__ outSc) {
    __shared__ float sm[SROWS * SSTRIDE];
    const int band = blockIdx.x, c0 = blockIdx.y * 32, b = blockIdx.z;
    const int t = threadIdx.x;
    const int rStart = band * 16 - 1;
    const u32 keyLo = (u32)band << 24, keyHi = (u32)(band + 1) << 24;
    const u32* aL = pixSorted + b * NN;
    const u32* aS = pcSorted + b * NN;
    u32 loL = lbound(aL, NN, keyLo), cL = lbound(aL, NN, keyHi) - loL;
    u32 loS = lbound(aS, NN, keyLo), cS = lbound(aS, NN, keyHi) - loS;
    const float* planes = fm + ((size_t)b * CC + c0) * HWV;
    const float* pcb = pc + (size_t)b * NN * 2;

    // ---- decode 2 L + 2 S points into named scalars (no arrays) ----
    int  Lo0 = 0, Lr2 = 0;  float Lw0 = 0, Lw1 = 0, Lw2 = 0, Lw3 = 0, Lwr = 0, Lic = 0;
    int  Mo0 = 0, Mr2 = 0;  float Mw0 = 0, Mw1 = 0, Mw2 = 0, Mw3 = 0, Mwr = 0, Mic = 0;
    int  So0 = 0, Sr1 = 0;  float Sv0 = 0, Sv1 = 0, Sw0 = 0, Sw1 = 0;
    int  To0 = 0, Tr1 = 0;  float Tv0 = 0, Tv1 = 0, Tw0 = 0, Tw1 = 0;
    {
        u32 jl = (u32)t;
        if (jl < cL) {
            u32 pix = aL[loL + jl] >> 12;
            int yi = (int)(pix >> 8), xi = (int)(pix & 255u);
            float cy = (float)yi / 255.0f, cx = (float)xi / 255.0f;   // exact ref pipeline
            int x = (int)(cx * 255.0f), y = (int)(cy * 255.0f);
            int x_min = max(x - 1, 0), x_max = min(x + 2, WW);
            int y_min = max(y - 1, 0), hgt = min(y + 2, HH) - y_min;
            int base2 = min(x_min & ~1, WW - 4);   // even: float2-aligned
            Lw0 = (base2 + 0 >= x_min && base2 + 0 < x_max) ? 1.0f : 0.0f;
            Lw1 = (base2 + 1 >= x_min && base2 + 1 < x_max) ? 1.0f : 0.0f;
            Lw2 = (base2 + 2 >= x_min && base2 + 2 < x_max) ? 1.0f : 0.0f;
            Lw3 = (base2 + 3 >= x_min && base2 + 3 < x_max) ? 1.0f : 0.0f;
            Lo0 = (y_min - rStart) * SSTRIDE + base2;
            Lr2 = ((hgt == 3) ? 2 : 0) * SSTRIDE;  Lwr = (hgt == 3) ? 1.0f : 0.0f;
            Lic = 1.0f / (float)((x_max - x_min) * hgt);
        }
        jl = 256u + (u32)t;
        if (jl < cL) {
            u32 pix = aL[loL + jl] >> 12;
            int yi = (int)(pix >> 8), xi = (int)(pix & 255u);
            float cy = (float)yi / 255.0f, cx = (float)xi / 255.0f;
            int x = (int)(cx * 255.0f), y = (int)(cy * 255.0f);
            int x_min = max(x - 1, 0), x_max = min(x + 2, WW);
            int y_min = max(y - 1, 0), hgt = min(y + 2, HH) - y_min;
            int base2 = min(x_min & ~1, WW - 4);
            Mw0 = (base2 + 0 >= x_min && base2 + 0 < x_max) ? 1.0f : 0.0f;
            Mw1 = (base2 + 1 >= x_min && base2 + 1 < x_max) ? 1.0f : 0.0f;
            Mw2 = (base2 + 2 >= x_min && base2 + 2 < x_max) ? 1.0f : 0.0f;
            Mw3 = (base2 + 3 >= x_min && base2 + 3 < x_max) ? 1.0f : 0.0f;
            Mo0 = (y_min - rStart) * SSTRIDE + base2;
            Mr2 = ((hgt == 3) ? 2 : 0) * SSTRIDE;  Mwr = (hgt == 3) ? 1.0f : 0.0f;
            Mic = 1.0f / (float)((x_max - x_min) * hgt);
        }
        u32 js = (u32)t;
        if (js < cS) {
            u32 sn = aS[loS + js] & 0xFFFu;
            float gx = pcb[2 * sn + 0], gy = pcb[2 * sn + 1];
            float fx = gx * 256.0f - 0.5f, fy = gy * 256.0f - 0.5f;   // exact
            float fx0 = floorf(fx), fy0 = floorf(fy);
            int x0 = (int)fx0, y0 = (int)fy0;
            float wx = fx - fx0, wy = fy - fy0;
            int xb = min(max(x0, 0), WW - 2);
            if (x0 < 0)            { Sv0 = wx;        Sv1 = 0.0f; }
            else if (x0 >= WW - 1) { Sv0 = 0.0f;      Sv1 = 1.0f - wx; }
            else                   { Sv0 = 1.0f - wx; Sv1 = wx; }
            Sw0 = (y0 >= 0)     ? (1.0f - wy) : 0.0f;
            Sw1 = (y0 + 1 < HH) ? wy          : 0.0f;
            int yc0 = min(max(y0, 0), HH - 1), yc1 = min(max(y0 + 1, 0), HH - 1);
            So0 = (yc0 - rStart) * SSTRIDE + xb;
            Sr1 = (yc1 - yc0) * SSTRIDE;
        }
        js = 256u + (u32)t;
        if (js < cS) {
            u32 sn = aS[loS + js] & 0xFFFu;
            float gx = pcb[2 * sn + 0], gy = pcb[2 * sn + 1];
            float fx = gx * 256.0f - 0.5f, fy = gy * 256.0f - 0.5f;
            float fx0 = floorf(fx), fy0 = floorf(fy);
            int x0 = (int)fx0, y0 = (int)fy0;
            float wx = fx - fx0, wy = fy - fy0;
            int xb = min(max(x0, 0), WW - 2);
            if (x0 < 0)            { Tv0 = wx;        Tv1 = 0.0f; }
            else if (x0 >= WW - 1) { Tv0 = 0.0f;      Tv1 = 1.0f - wx; }
            else                   { Tv0 = 1.0f - wx; Tv1 = wx; }
            Tw0 = (y0 >= 0)     ? (1.0f - wy) : 0.0f;
            Tw1 = (y0 + 1 < HH) ? wy          : 0.0f;
            int yc0 = min(max(y0, 0), HH - 1), yc1 = min(max(y0 + 1, 0), HH - 1);
            To0 = (yc0 - rStart) * SSTRIDE + xb;
            Tr1 = (yc1 - yc0) * SSTRIDE;
        }
    }

    float4 g0, g1, g2, g3, g4;
    STAGE_LOAD(planes)
    STAGE_WRITE()
    __syncthreads();

    #pragma unroll 1
    for (int j = 0; j < 32; ++j) {
        if (j + 1 < 32) { const float* np = planes + (size_t)(j + 1) * HWV; STAGE_LOAD(np) }
        // ---- taps from LDS, written immediately (sorted-position layout) ----
        float* oL = outLc + ((size_t)(b * CC + c0 + j)) * NN + loL;
        float* oS = outSc + ((size_t)(b * CC + c0 + j)) * NN + loS;
        if ((u32)t < cL) {
            float2 a0 = *(const float2*)(sm + Lo0);
            float2 b0 = *(const float2*)(sm + Lo0 + 2);
            float2 a1 = *(const float2*)(sm + Lo0 + SSTRIDE);
            float2 b1 = *(const float2*)(sm + Lo0 + SSTRIDE + 2);
            float2 a2 = *(const float2*)(sm + Lo0 + Lr2);
            float2 b2 = *(const float2*)(sm + Lo0 + Lr2 + 2);
            float r0 = a0.x * Lw0 + a0.y * Lw1 + b0.x * Lw2 + b0.y * Lw3;
            float r1 = a1.x * Lw0 + a1.y * Lw1 + b1.x * Lw2 + b1.y * Lw3;
            float r2 = a2.x * Lw0 + a2.y * Lw1 + b2.x * Lw2 + b2.y * Lw3;
            oL[t] = (r0 + r1 + Lwr * r2) * Lic;
        }
        if (256u + (u32)t < cL) {
            float2 a0 = *(const float2*)(sm + Mo0);
            float2 b0 = *(const float2*)(sm + Mo0 + 2);
            float2 a1 = *(const float2*)(sm + Mo0 + SSTRIDE);
            float2 b1 = *(const float2*)(sm + Mo0 + SSTRIDE + 2);
            float2 a2 = *(const float2*)(sm + Mo0 + Mr2);
            float2 b2 = *(const float2*)(sm + Mo0 + Mr2 + 2);
            float r0 = a0.x * Mw0 + a0.y * Mw1 + b0.x * Mw2 + b0.y * Mw3;
            float r1 = a1.x * Mw0 + a1.y * Mw1 + b1.x * Mw2 + b1.y * Mw3;
            float r2 = a2.x * Mw0 + a2.y * Mw1 + b2.x * Mw2 + b2.y * Mw3;
            oL[256 + t] = (r0 + r1 + Mwr * r2) * Mic;
        }
        if ((u32)t < cS) {
            oS[t] = Sw0 * (sm[So0] * Sv0 + sm[So0 + 1] * Sv1)
                  + Sw1 * (sm[So0 + Sr1] * Sv0 + sm[So0 + Sr1 + 1] * Sv1);
        }
        if (256u + (u32)t < cS) {
            oS[256 + t] = Tw0 * (sm[To0] * Tv0 + sm[To0 + 1] * Tv1)
                        + Tw1 * (sm[To0 + Tr1] * Tv0 + sm[To0 + Tr1 + 1] * Tv1);
        }
        __syncthreads();
        if (j + 1 < 32) { STAGE_WRITE() }
        __syncthreads();
    }

    // ---- overflow epilogue (cL/cS > 512: >16 sigma, never in practice) ----
    for (u32 jl = 512 + (u32)t; jl < cL; jl += 256) {
        u32 pix = aL[loL + jl] >> 12;
        int yi = (int)(pix >> 8), xi = (int)(pix & 255u);
        float cy = (float)yi / 255.0f, cx = (float)xi / 255.0f;
        int x = (int)(cx * 255.0f), y = (int)(cy * 255.0f);
        int x_min = max(x - 1, 0), x_max = min(x + 2, WW);
        int y_min = max(y - 1, 0), y_max = min(y + 2, HH);
        float ic = 1.0f / (float)((x_max - x_min) * (y_max - y_min));
        for (int j = 0; j < 32; ++j) {
            const float* p = planes + (size_t)j * HWV;
            float s = 0.0f;
            for (int yy = y_min; yy < y_max; ++yy)
                for (int xx = x_min; xx < x_max; ++xx) s += p[yy * WW + xx];
            outLc[((size_t)(b * CC + c0 + j)) * NN + loL + jl] = s * ic;
        }
    }
    for (u32 js = 512 + (u32)t; js < cS; js += 256) {
        u32 sn = aS[loS + js] & 0xFFFu;
        float gx = pcb[2 * sn + 0], gy = pcb[2 * sn + 1];
        float fx = gx * 256.0f - 0.5f, fy = gy * 256.0f - 0.5f;
        float fx0 = floorf(fx), fy0 = floorf(fy);
        int x0 = (int)fx0, y0 = (int)fy0;
        float wx = fx - fx0, wy = fy - fy0;
        int xb = min(max(x0, 0), WW - 2);
        float v0, v1, r0, r1;
        if (x0 < 0)            { v0 = wx;        v1 = 0.0f; }
        else if (x0 >= WW - 1) { v0 = 0.0f;      v1 = 1.0f - wx; }
        else                   { v0 = 1.0f - wx; v1 = wx; }
        r0 = (y0 >= 0)     ? (1.0f - wy) : 0.0f;
        r1 = (y0 + 1 < HH) ? wy          : 0.0f;
        int yc0 = min(max(y0, 0), HH - 1), yc1 = min(max(y0 + 1, 0), HH - 1);
        int o0 = yc0 * WW + xb, o1 = yc1 * WW + xb;
        for (int j = 0; j < 32; ++j) {
            const float* p = planes + (size_t)j * HWV;
            outSc[((size_t)(b * CC + c0 + j)) * NN + loS + js] =
                r0 * (p[o0] * v0 + p[o0 + 1] * v1) + r1 * (p[o1] * v0 + p[o1 + 1] * v1);
        }
    }
}

// ---------------------------------------------------------------------------
// K4: unpermute L: outL[b][c][rank[spos]] = outLc[b][c][spos] via LDS scatter.
__global__ __launch_bounds__(256) void unpermL_k(const float* __restrict__ outLc,
                                                 const u32* __restrict__ pixSorted,
                                                 float* __restrict__ outL) {
    __shared__ float row[NN];
    const int c = blockIdx.x, b = blockIdx.y;
    const int t = threadIdx.x;
    const float* in = outLc + ((size_t)(b * CC + c)) * NN;
    for (int j = t; j < NN; j += 256)
        row[pixSorted[b * NN + j] & 0xFFFu] = in[j];
    __syncthreads();
    float* o = outL + ((size_t)(b * CC + c)) * NN;
    for (int i = t; i < NN; i += 256) o[i] = row[i];
}

// ---------------------------------------------------------------------------
// K5: unpermute S: outS[b][n[spos]][c] = outSc[b][c][spos] (tile transpose).
__global__ __launch_bounds__(256) void unpermS_k(const float* __restrict__ outSc,
                                                 const u32* __restrict__ pcSorted,
                                                 float* __restrict__ outS) {
    __shared__ float tile[32][257];
    __shared__ u32 ns[256];
    const int j0 = blockIdx.x * 256, c0 = blockIdx.y * 32, b = blockIdx.z;
    const int t = threadIdx.x;
    ns[t] = pcSorted[b * NN + j0 + t] & 0xFFFu;
    for (int i = 0; i < 32; ++i)
        tile[i][t] = outSc[((size_t)(b * CC + c0 + i)) * NN + j0 + t];
    __syncthreads();
    for (int idx = t; idx < 8192; idx += 256) {
        int p = idx >> 5, k = idx & 31;
        outS[((size_t)b * NN + ns[p]) * CC + c0 + k] = tile[k][p];
    }
}

// ---------------------------------------------------------------------------
// Fallback kernels (no-ws path): round-13 proven pipeline.
__global__ void build_keys_k(const float* __restrict__ pm, const int* __restrict__ em,
                             u64* __restrict__ keys) {
    int i = blockIdx.x * blockDim.x + threadIdx.x;
    float f = (em[i] == 1) ? -fabsf(pm[i]) : -1e30f;
    u32 u = __float_as_uint(f);
    u32 k = (u & 0x80000000u) ? ~u : (u | 0x80000000u);
    u32 pix = (u32)i & 0xFFFFu;
    keys[i] = ((u64)k << 16) | (u64)(0xFFFFu - pix);
}

__global__ __launch_bounds__(1024) void topk_sortpc_old_k(const u64* __restrict__ keys,
                                                          const float* __restrict__ pc,
                                                          u32* __restrict__ stash,
                                                          u32* __restrict__ pixSorted,
                                                          u32* __restrict__ pcSorted) {
    __shared__ u64 sel[NN];
    __shared__ u64 bm[1024];
    __shared__ u32 wp[1024];
    __shared__ u32 s_digit, s_rem, s_cnt;
    const int t = threadIdx.x;
    if (blockIdx.x < 8) {
        const int b = blockIdx.x;
        const u64* kb = keys + (size_t)b * HWV;
        u32* hist = (u32*)sel;
        u64 prefix = 0ULL;
        u32 remaining = NN;
        for (int r = 0; r < 4; ++r) {
            int shift = 36 - 12 * r;
            #pragma unroll
            for (int q = 0; q < 4; ++q) hist[t + q * 1024] = 0u;
            __syncthreads();
            for (int i = t; i < HWV; i += 1024) {
                u64 K = kb[i];
                if ((K >> (shift + 12)) == prefix)
                    atomicAdd(&hist[(u32)((K >> shift) & 0xFFFULL)], 1u);
            }
            __syncthreads();
            for (int off = 1; off < 4096; off <<= 1) {
                u32 v[4];
                #pragma unroll
                for (int q = 0; q < 4; ++q) {
                    int i = t + q * 1024;
                    v[q] = hist[i];
                    if (i + off < 4096) v[q] += hist[i + off];
                }
                __syncthreads();
                #pragma unroll
                for (int q = 0; q < 4; ++q) hist[t + q * 1024] = v[q];
                __syncthreads();
            }
            #pragma unroll
            for (int q = 0; q < 4; ++q) {
                int d = t + q * 1024;
                u32 ge = hist[d];
                u32 gt = (d < 4095) ? hist[d + 1] : 0u;
                if (ge >= remaining && gt < remaining) { s_digit = (u32)d; s_rem = remaining - gt; }
            }
            __syncthreads();
            prefix = (prefix << 12) | (u64)s_digit;
            remaining = s_rem;
            __syncthreads();
        }
        if (t == 0) s_cnt = 0u;
        __syncthreads();
        for (int i = t; i < HWV; i += 1024) {
            u64 K = kb[i];
            if (K >= prefix) { u32 p = atomicAdd(&s_cnt, 1u); sel[p] = K; }
        }
        __syncthreads();
        for (int k = 2; k <= NN; k <<= 1) {
            for (int j = k >> 1; j > 0; j >>= 1) {
                for (int i = t; i < NN; i += 1024) {
                    int l = i ^ j;
                    if (l > i) {
                        u64 a = sel[i], c = sel[l];
                        bool asc = ((i & k) == 0);
                        if ((a < c) == asc) { sel[i] = c; sel[l] = a; }
                    }
                }
                __syncthreads();
            }
        }
        bm[t] = 0ULL;
        __syncthreads();
        #pragma unroll
        for (int q = 0; q < 4; ++q) {
            int r = t + q * 1024;
            u32 pix = 0xFFFFu - (u32)(sel[r] & 0xFFFFULL);
            stash[b * NN + r] = pix;
            atomicOr(&bm[pix >> 6], 1ULL << (pix & 63));
        }
        __syncthreads();
        wp[t] = (u32)__popcll(bm[t]);
        __syncthreads();
        for (int off = 1; off < 1024; off <<= 1) {
            u32 v = wp[t];
            if (t >= off) v += wp[t - off];
            __syncthreads();
            wp[t] = v;
            __syncthreads();
        }
        #pragma unroll
        for (int q = 0; q < 4; ++q) {
            int r = t + q * 1024;
            u32 pix = 0xFFFFu - (u32)(sel[r] & 0xFFFFULL);
            int w = (int)(pix >> 6);
            u32 pos = wp[w] - (u32)__popcll(bm[w])
                    + (u32)__popcll(bm[w] & ((1ULL << (pix & 63)) - 1ULL));
            pixSorted[b * NN + pos] = (pix << 12) | (u32)r;
        }
    } else {
        const int b = blockIdx.x - 8;
        u32* cellArr = (u32*)sel;
        u32* hist256 = wp;
        u32* cnt     = (u32*)bm;
        if (t < 256) { hist256[t] = 0u; cnt[t] = 0u; }
        __syncthreads();
        for (int n = t; n < NN; n += 1024) {
            float gx = pc[((size_t)b * NN + n) * 2 + 0];
            float gy = pc[((size_t)b * NN + n) * 2 + 1];
            float fx = gx * 256.0f - 0.5f;
            float fy = gy * 256.0f - 0.5f;
            int x0 = (int)floorf(fx), y0 = (int)floorf(fy);
            int xc = min(max(x0, 0), 255), yc = min(max(y0, 0), 255);
            cellArr[n] = ((u32)(yc * 256 + xc) << 12) | (u32)n;
            atomicAdd(&hist256[yc], 1u);
        }
        __syncthreads();
        for (int off = 1; off < 256; off <<= 1) {
            u32 v = 0;
            if (t < 256) { v = hist256[t]; if (t >= off) v += hist256[t - off]; }
            __syncthreads();
            if (t < 256) hist256[t] = v;
            __syncthreads();
        }
        for (int n = t; n < NN; n += 1024) {
            u32 pk = cellArr[n];
            u32 yc = pk >> 20;
            u32 base = (yc > 0) ? hist256[yc - 1] : 0u;
            u32 pos = base + atomicAdd(&cnt[yc], 1u);
            pcSorted[b * NN + pos] = pk;
        }
    }
}

template<int MODE>
__global__ __launch_bounds__(256, 4) void gather_k(const float* __restrict__ fm,
                                                   const float* __restrict__ pc,
                                                   const u32* __restrict__ pixSorted,
                                                   const u32* __restrict__ pcSorted,
                                                   float* __restrict__ outLp,
                                                   float* __restrict__ outS) {
    __shared__ float tile[256][33];
    __shared__ u32 pidx[256];
    const int b = blockIdx.z, j0 = blockIdx.x * 256, t = threadIdx.x;
    bool doL = (MODE == 1); int c0 = blockIdx.y * 32;
    const float* planes = fm + ((size_t)b * CC + c0) * HWV;
    if (doL) {
        u32 packed = pixSorted[b * NN + j0 + t];
        u32 pix = packed >> 12;
        pidx[t] = packed & 0xFFFu;
        int yi = (int)(pix >> 8), xi = (int)(pix & 255u);
        float cy = (float)yi / 255.0f, cx = (float)xi / 255.0f;
        int x = (int)(cx * 255.0f), y = (int)(cy * 255.0f);
        int x_min = max(x - 1, 0), x_max = min(x + 2, WW);
        int y_min = max(y - 1, 0), y_max = min(y + 2, HH);
        int base = min(x_min & ~3, WW - 8);
        float w8[8];
        #pragma unroll
        for (int i = 0; i < 8; ++i)
            w8[i] = (base + i >= x_min && base + i < x_max) ? 1.0f : 0.0f;
        float wr2 = (y_min + 2 < y_max) ? 1.0f : 0.0f;
        int o0 = y_min * WW + base, o1 = o0 + WW;
        int o2 = min(y_min + 2, HH - 1) * WW + base;
        float invc = 1.0f / (float)((x_max - x_min) * (y_max - y_min));
        #pragma unroll 2
        for (int j = 0; j < 32; ++j) {
            const float* p = planes + (size_t)j * HWV;
            float4 a0 = *(const float4*)(p + o0), b0 = *(const float4*)(p + o0 + 4);
            float4 a1 = *(const float4*)(p + o1), b1 = *(const float4*)(p + o1 + 4);
            float4 a2 = *(const float4*)(p + o2), b2 = *(const float4*)(p + o2 + 4);
            float s0 = a0.x * w8[0] + a0.y * w8[1] + a0.z * w8[2] + a0.w * w8[3]
                     + b0.x * w8[4] + b0.y * w8[5] + b0.z * w8[6] + b0.w * w8[7];
            float s1 = a1.x * w8[0] + a1.y * w8[1] + a1.z * w8[2] + a1.w * w8[3]
                     + b1.x * w8[4] + b1.y * w8[5] + b1.z * w8[6] + b1.w * w8[7];
            float s2 = a2.x * w8[0] + a2.y * w8[1] + a2.z * w8[2] + a2.w * w8[3]
                     + b2.x * w8[4] + b2.y * w8[5] + b2.z * w8[6] + b2.w * w8[7];
            tile[t][j] = (s0 + s1 + wr2 * s2) * invc;
        }
        __syncthreads();
        for (int idx = t; idx < 8192; idx += 256) {
            int p = idx >> 5, k = idx & 31;
            outLp[((size_t)b * NN + pidx[p]) * CC + c0 + k] = tile[p][k];
        }
    } else {
        int n = (int)(pcSorted[b * NN + j0 + t] & 0xFFFu);
        pidx[t] = (u32)n;
        float gx = pc[((size_t)b * NN + n) * 2 + 0];
        float gy = pc[((size_t)b * NN + n) * 2 + 1];
        float fx = gx * 256.0f - 0.5f, fy = gy * 256.0f - 0.5f;
        float fx0 = floorf(fx), fy0 = floorf(fy);
        int x0 = (int)fx0, y0 = (int)fy0;
        float wx = fx - fx0, wy = fy - fy0;
        int xb = min(max(x0, 0), WW - 2);
        float wv0, wv1;
        if (x0 < 0)            { wv0 = wx;        wv1 = 0.0f; }
        else if (x0 >= WW - 1) { wv0 = 0.0f;      wv1 = 1.0f - wx; }
        else                   { wv0 = 1.0f - wx; wv1 = wx; }
        float wr0 = (y0 >= 0)     ? (1.0f - wy) : 0.0f;
        float wr1 = (y0 + 1 < HH) ? wy          : 0.0f;
        int yc0 = min(max(y0, 0), HH - 1), yc1 = min(max(y0 + 1, 0), HH - 1);
        int o0 = yc0 * WW + xb, o1 = yc1 * WW + xb;
        #pragma unroll 4
        for (int j = 0; j < 32; ++j) {
            const float* p = planes + (size_t)j * HWV;
            tile[t][j] = wr0 * (p[o0] * wv0 + p[o0 + 1] * wv1)
                       + wr1 * (p[o1] * wv0 + p[o1 + 1] * wv1);
        }
        __syncthreads();
        for (int idx = t; idx < 8192; idx += 256) {
            int p = idx >> 5, k = idx & 31;
            outS[((size_t)b * NN + pidx[p]) * CC + c0 + k] = tile[p][k];
        }
    }
}

__global__ __launch_bounds__(256) void transpose_k(const float* __restrict__ outLp,
                                                   float* __restrict__ outL) {
    __shared__ float tile[256][33];
    const int b = blockIdx.z, c0 = blockIdx.y * 32, r0 = blockIdx.x * 256;
    const int t = threadIdx.x;
    for (int idx = t; idx < 8192; idx += 256) {
        int p = idx >> 5, k = idx & 31;
        tile[p][k] = outLp[((size_t)b * NN + r0 + p) * CC + c0 + k];
    }
    __syncthreads();
    for (int idx = t; idx < 8192; idx += 256) {
        int cl = idx >> 8, col = idx & 255;
        outL[((size_t)b * CC + c0 + cl) * NN + r0 + col] = tile[col][cl];
    }
}

__global__ void emit_k(const u32* __restrict__ stash, float* __restrict__ outCoord,
                       float* __restrict__ outIdx) {
    int i = blockIdx.x * blockDim.x + threadIdx.x;
    u32 p = stash[i];
    u32 yi = p >> 8, xi = p & 255u;
    outCoord[(size_t)i * 2 + 0] = (float)yi / 255.0f;
    outCoord[(size_t)i * 2 + 1] = (float)xi / 255.0f;
    outIdx[i] = (float)p;
}

extern "C" void kernel_launch(void* const* d_in, const int* in_sizes, int n_in,
                              void* d_out, int out_size, void* d_ws, size_t ws_size,
                              hipStream_t stream) {
    const float* fm = (const float*)d_in[0];   // (8,256,256,256) f32
    const float* pm = (const float*)d_in[1];   // (8,1,256,256) f32
    const int*   em = (const int*)d_in[2];     // (8,256,256) i32
    const float* pc = (const float*)d_in[3];   // (8,4096,2) f32
    (void)in_sizes; (void)n_in; (void)out_size;

    float* out      = (float*)d_out;
    float* outL     = out;                         // local_feats (8,256,4096)
    float* outS     = out + (size_t)8388608;       // sampled     (8,4096,256)
    float* outCoord = out + (size_t)16777216;      // coords      (8,4096,2)
    float* outIdx   = out + (size_t)16842752;      // idx         (8,4096)

    const size_t need_ws = (size_t)80 * 1024 * 1024;
    bool ws_ok = ws_size >= need_ws;

    if (ws_ok) {
        char* w = (char*)d_ws;
        u64* keys      = (u64*)w;                                // 4 MB
        u32* ghist     = (u32*)(w + (size_t)4096 * 1024);        // 128 KB
        u32* pixSorted = (u32*)(w + (size_t)4300 * 1024);        // 128 KB
        u32* pcSorted  = (u32*)(w + (size_t)4600 * 1024);        // 128 KB
        float* outLc   = (float*)(w + (size_t)5  * 1024 * 1024); // 33.5 MB
        float* outSc   = (float*)(w + (size_t)40 * 1024 * 1024); // 33.5 MB

        hipLaunchKernelGGL(zero_hist_k, dim3(32), dim3(1024), 0, stream, ghist);
        hipLaunchKernelGGL(build_keys_hist_k, dim3(2048), dim3(256), 0, stream,
                           pm, em, keys, ghist);
        hipLaunchKernelGGL(topk_sortpc_k, dim3(16), dim3(1024), 0, stream,
                           keys, ghist, pc, pixSorted, pcSorted, outCoord, outIdx);
        hipLaunchKernelGGL(plane_gather_k, dim3(16, 8, 8), dim3(256), 0, stream,
                           fm, pc, pixSorted, pcSorted, outLc, outSc);
        hipLaunchKernelGGL(unpermL_k, dim3(256, 8), dim3(256), 0, stream,
                           outLc, pixSorted, outL);
        hipLaunchKernelGGL(unpermS_k, dim3(16, 8, 8), dim3(256), 0, stream,
                           outSc, pcSorted, outS);
    } else {
        // alias scheme: keys/outLp in seg1 (final writer = gather<2>),
        // pixSorted/pcSorted in seg2 (final writer = emit), stash in seg3.
        u64* keys      = (u64*)outS;
        u32* stash     = (u32*)outIdx;
        u32* pixSorted = (u32*)outCoord;
        u32* pcSorted  = pixSorted + 32768;
        float* outLp   = outS;

        hipLaunchKernelGGL(build_keys_k, dim3(2048), dim3(256), 0, stream, pm, em, keys);
        hipLaunchKernelGGL(topk_sortpc_old_k, dim3(16), dim3(1024), 0, stream,
                           keys, pc, stash, pixSorted, pcSorted);
        hipLaunchKernelGGL((gather_k<1>), dim3(16, 8, 8), dim3(256), 0, stream,
                           fm, pc, pixSorted, pcSorted, outLp, outS);
        hipLaunchKernelGGL(transpose_k, dim3(16, 8, 8), dim3(256), 0, stream, outLp, outL);
        hipLaunchKernelGGL((gather_k<2>), dim3(16, 8, 8), dim3(256), 0, stream,
                           fm, pc, pixSorted, pcSorted, outS, outS);
        hipLaunchKernelGGL(emit_k, dim3(128), dim3(256), 0, stream, stash, outCoord, outIdx);
    }
}